// Round 9
// baseline (218.442 us; speedup 1.0000x reference)
//
#include <hip/hip_runtime.h>
#include <stdint.h>

#define TSEQ 2048
#define NB 2
#define EMB 1024
#define NHEAD 16
#define HDIM 64
#define NT (TSEQ / 64)            // 32 key-tiles per block (full softmax)
// 0.125 (D^-0.5) * log2(e), folded into Q at the in-proj epilogue
#define QSCALE 0.18033688f

typedef __bf16 bf16x8 __attribute__((ext_vector_type(8)));
typedef __bf16 bf16x4 __attribute__((ext_vector_type(4)));
typedef float f32x4 __attribute__((ext_vector_type(4)));
typedef float f32x16 __attribute__((ext_vector_type(16)));
typedef unsigned int u32x4 __attribute__((ext_vector_type(4)));

// async 16B global->LDS. lds base must be wave-uniform; HW scatters lane*16.
__device__ __forceinline__ void gload_lds16(const void* g, void* lds) {
    __builtin_amdgcn_global_load_lds(
        (const __attribute__((address_space(1))) unsigned int*)g,
        (__attribute__((address_space(3))) unsigned int*)lds, 16, 0, 0);
}

__device__ __forceinline__ float fast_exp2(float x) {
#if __has_builtin(__builtin_amdgcn_exp2f)
    return __builtin_amdgcn_exp2f(x);   // raw v_exp_f32; inputs bounded
#else
    return exp2f(x);
#endif
}

// packed f32 pair -> bf16x2 in one u32 (lo in [15:0], hi in [31:16])
__device__ __forceinline__ unsigned cvt_pk_bf16(float lo, float hi) {
    unsigned r;
    asm("v_cvt_pk_bf16_f32 %0, %1, %2" : "=v"(r) : "v"(lo), "v"(hi));
    return r;
}

// a[32:63] <-> b[0:31]
__device__ __forceinline__ void swap32(unsigned& a, unsigned& b) {
    asm("v_permlane32_swap_b32 %0, %1" : "+v"(a), "+v"(b));
}

__device__ __forceinline__ bf16x8 as_bf16x8(u32x4 u) {
    union { u32x4 u; bf16x8 h; } c;
    c.u = u;
    return c.h;
}

// ---------------------------------------------------------------------------
// merged prep: bid<4096 -> cvt x (4096x1024 f32 -> bf16);
// else transpose+cvt weights f32 [1024][sn] -> bf16 [sn][1024].
// grid 4096 + 128*32 = 8192, block 256.
// ---------------------------------------------------------------------------
__global__ __launch_bounds__(256) void prep_kernel(
    const float* __restrict__ x, const float* __restrict__ w_in,
    const float* __restrict__ w_out,
    __bf16* __restrict__ xb, __bf16* __restrict__ wiT, __bf16* __restrict__ whT)
{
    __shared__ float tile[32][33];
    int bid = blockIdx.x;
    const int tid = threadIdx.x;
    if (bid < 4096) {
        const size_t idx = ((size_t)bid * 256 + tid) * 4;
        float4 v = *(const float4*)(x + idx);
        bf16x4 o = { (__bf16)v.x, (__bf16)v.y, (__bf16)v.z, (__bf16)v.w };
        *(bf16x4*)(xb + idx) = o;
        return;
    }
    bid -= 4096;
    int bx = bid & 127;            // 0..127
    const int by = bid >> 7;       // 0..31
    const float* src; __bf16* dst; int sn;
    if (bx < 96) { src = w_in;  dst = wiT; sn = 3072; }
    else         { bx -= 96; src = w_out; dst = whT; sn = 1024; }
    const int tx = tid & 31, ty = tid >> 5;
    #pragma unroll
    for (int i = 0; i < 4; ++i)
        tile[ty + i * 8][tx] = src[(size_t)(by * 32 + ty + i * 8) * sn + bx * 32 + tx];
    __syncthreads();
    #pragma unroll
    for (int i = 0; i < 4; ++i) {
        float v = tile[tx][ty + i * 8];
        dst[(size_t)(bx * 32 + ty + i * 8) * 1024 + by * 32 + tx] = (__bf16)v;
    }
}

// ---------------------------------------------------------------------------
// bf16 MFMA GEMM for in-projection. 128x128 tile, BK=64. sec = n0>>10 is
// block-uniform. Q (pre-scaled) and K stored coalesced [bh][t][d]; V blocks
// route through an LDS transpose (overlaid on dead As/Bs, odd stride 131)
// and store Vt [bh][d][t] DIRECTLY. grid (24, 32), LDS 33.5KB.
// ---------------------------------------------------------------------------
__global__ __launch_bounds__(256) void gemm_qkv_kernel(
    const __bf16* __restrict__ A, const __bf16* __restrict__ BT,
    const float* __restrict__ bias,
    __bf16* __restrict__ Oq, __bf16* __restrict__ Ok, __bf16* __restrict__ Vt)
{
    __shared__ __align__(16) char smem[128 * 131 * 2];  // 33536B
    __bf16* As = (__bf16*)smem;              // 128x64, main loop
    __bf16* Bs = (__bf16*)(smem + 16384);    // 128x64, main loop
    __bf16* Tt = (__bf16*)smem;              // 128x131, V epilogue (overlay)

    const int tid = threadIdx.x;
    const int wave = tid >> 6, lane = tid & 63;
    const int l16 = lane & 15, quad = lane >> 4;
    const int wm = wave >> 1, wn = wave & 1;
    const int m0 = blockIdx.y * 128, n0 = blockIdx.x * 128;

    f32x4 acc[4][4];
    #pragma unroll
    for (int mt = 0; mt < 4; ++mt)
        #pragma unroll
        for (int nt = 0; nt < 4; ++nt)
            #pragma unroll
            for (int r = 0; r < 4; ++r) acc[mt][nt][r] = 0.f;

    int smrow[4], schunk[4], sbase[4];
    #pragma unroll
    for (int i = 0; i < 4; ++i) {
        int linear = (wave * 4 + i) * 64 + lane;
        smrow[i] = linear >> 3;
        schunk[i] = (linear & 7) ^ (smrow[i] & 7);
        sbase[i] = (wave * 4 + i) * 512;
    }

    for (int k0 = 0; k0 < 1024; k0 += 64) {
        #pragma unroll
        for (int i = 0; i < 4; ++i) {
            gload_lds16(A + (size_t)(m0 + smrow[i]) * 1024 + k0 + schunk[i] * 8,
                        As + sbase[i]);
            gload_lds16(BT + (size_t)(n0 + smrow[i]) * 1024 + k0 + schunk[i] * 8,
                        Bs + sbase[i]);
        }
        __syncthreads();
        #pragma unroll
        for (int kk = 0; kk < 2; ++kk) {
            bf16x8 am[4], bn[4];
            #pragma unroll
            for (int mt = 0; mt < 4; ++mt) {
                int row = wm * 64 + mt * 16 + l16;
                int c = (kk * 4 + quad) ^ (row & 7);
                am[mt] = *(const bf16x8*)(As + row * 64 + c * 8);
            }
            #pragma unroll
            for (int nt = 0; nt < 4; ++nt) {
                int row = wn * 64 + nt * 16 + l16;
                int c = (kk * 4 + quad) ^ (row & 7);
                bn[nt] = *(const bf16x8*)(Bs + row * 64 + c * 8);
            }
            #pragma unroll
            for (int mt = 0; mt < 4; ++mt)
                #pragma unroll
                for (int nt = 0; nt < 4; ++nt)
                    acc[mt][nt] = __builtin_amdgcn_mfma_f32_16x16x32_bf16(
                        am[mt], bn[nt], acc[mt][nt], 0, 0, 0);
        }
        __syncthreads();
    }

    const int sec = n0 >> 10;                // block-uniform: 0=Q, 1=K, 2=V
    if (sec < 2) {
        __bf16* __restrict__ O = (sec == 0) ? Oq : Ok;
        const float scale = (sec == 0) ? QSCALE : 1.f;
        #pragma unroll
        for (int nt = 0; nt < 4; ++nt) {
            const int col = n0 + wn * 64 + nt * 16 + l16;
            const float bv = bias[col];
            const int f = col & 1023;
            const int h = f >> 6, d = f & 63;
            #pragma unroll
            for (int mt = 0; mt < 4; ++mt)
                #pragma unroll
                for (int r = 0; r < 4; ++r) {
                    const int row = m0 + wm * 64 + mt * 16 + quad * 4 + r;
                    const float v = (acc[mt][nt][r] + bv) * scale;
                    const int t = row >> 1, b = row & 1;
                    const int bh = b * NHEAD + h;
                    O[((size_t)bh * TSEQ + t) * HDIM + d] = (__bf16)v;
                }
        }
    } else {
        // V: acc -> LDS (stride 131, odd -> transpose reads 2-way max),
        // barrier, transposed coalesced store to Vt [bh][d][t]
        #pragma unroll
        for (int nt = 0; nt < 4; ++nt) {
            const int lc = wn * 64 + nt * 16 + l16;
            const float bv = bias[n0 + lc];
            #pragma unroll
            for (int mt = 0; mt < 4; ++mt)
                #pragma unroll
                for (int r = 0; r < 4; ++r) {
                    const int ml = wm * 64 + mt * 16 + quad * 4 + r;
                    Tt[ml * 131 + lc] = (__bf16)(acc[mt][nt][r] + bv);
                }
        }
        __syncthreads();
        // wave -> (b, h_local); rows ml = 2*t_local + b, cols lc = hl*64 + d
        const int b = wave & 1, hl = wave >> 1;
        const int bh = b * NHEAD + ((n0 - 2048) >> 6) + hl;
        const int t0g = m0 >> 1;
        __bf16* dstbase = Vt + (size_t)bh * HDIM * TSEQ + t0g;
        const int dq = lane >> 3;          // d low bits 0..7
        const int tb = (lane & 7) * 8;     // t chunk base
        #pragma unroll
        for (int p = 0; p < 8; ++p) {
            const int d = dq + 8 * p;
            bf16x8 o;
            #pragma unroll
            for (int jj = 0; jj < 8; ++jj)
                o[jj] = Tt[(2 * (tb + jj) + b) * 131 + hl * 64 + d];
            *(bf16x8*)(dstbase + (size_t)d * TSEQ + tb) = o;
        }
    }
}

// ---------------------------------------------------------------------------
// MFMA flash attention v13: v12 minus the Vs LDS staging. V fragments are
// read DIRECTLY from global Vt (L2-resident by XCD swizzle: 4bh x 768KB =
// 3MB per XCD L2) as 8x global_load_dwordx4 per tile, issued right after the
// barrier so QK^T+softmax (~400cy) hides L2 latency; compiler's vmcnt before
// PV leaves the K-prefetch gload_lds in flight. Removes half the ds_read
// traffic and all V bank conflicts -- LDS pipe (was ~60-78% busy, the top
// resource) drops off the critical path. LDS 16.5KB, VGPR ~100.
// Fused-normalize epilogue unchanged. Grid 512 flat, XCD-bijective.
// ---------------------------------------------------------------------------
__global__ __launch_bounds__(256, 2) void attn_mfma_kernel(
    const __bf16* __restrict__ Q, const __bf16* __restrict__ K,
    const __bf16* __restrict__ Vt, __bf16* __restrict__ Ob)
{
    __shared__ __align__(16) __bf16 Ks[2][64 * 64];     // 16KB
    __shared__ float Linv[4][32];                       // 512B

    const int tid  = threadIdx.x;
    const int wave = tid >> 6;
    const int lane = tid & 63;
    const int l31  = lane & 31;
    const int hi   = lane >> 5;
    const int m7   = l31 & 7;

    // XCD-aware decode: hardware assigns XCD = blockIdx.x % 8 (round-robin).
    const int lid = blockIdx.x;        // 0..511
    const int xcd = lid & 7;
    const int j   = lid >> 3;          // 0..63 within XCD
    const int bh  = xcd * 4 + (j >> 4);    // 0..31
    const int qb  = j & 15;            // q-tile 0..15

    const int q0 = qb * 128 + wave * 32;

    // Q fragments (B-operand): col = q = l31, contraction d = 16c + 8hi + j
    bf16x8 qf[4];
    {
        const __bf16* Qrow = Q + ((size_t)bh * TSEQ + q0 + l31) * HDIM + 8 * hi;
        #pragma unroll
        for (int c = 0; c < 4; ++c)
            qf[c] = *(const bf16x8*)(Qrow + 16 * c);
    }

    // O accumulators: per d-tile dt, lane holds col d = 32*dt + l31,
    // rows q = (r&3) + 8*(r>>2) + 4*hi
    f32x16 Oacc[2];
    #pragma unroll
    for (int dt = 0; dt < 2; ++dt)
        #pragma unroll
        for (int r = 0; r < 16; ++r) Oacc[dt][r] = 0.f;
    float l4[4] = {0.f, 0.f, 0.f, 0.f};

    const __bf16* Kbase = K + (size_t)bh * TSEQ * HDIM;
    // per-lane V base: row d = dt*32 + l31, 16B chunk at t = kt*64+ks*16+hi*8
    const __bf16* Vrow0 = Vt + ((size_t)bh * HDIM + l31) * TSEQ + hi * 8;
    const __bf16* Vrow1 = Vrow0 + (size_t)32 * TSEQ;

    int srow[2], schk[2];
    #pragma unroll
    for (int i = 0; i < 2; ++i) {
        const int s = wave * 2 + i;
        srow[i] = s * 8 + (lane >> 3);
        schk[i] = (lane & 7) ^ (srow[i] & 7);
    }

#define STAGE(buf, kt)                                                        \
    {                                                                         \
        _Pragma("unroll")                                                     \
        for (int i = 0; i < 2; ++i) {                                         \
            const int s = wave * 2 + i;                                       \
            gload_lds16(Kbase + (size_t)((kt) * 64 + srow[i]) * HDIM          \
                            + schk[i] * 8,                                    \
                        &Ks[buf][s * 512]);                                   \
        }                                                                     \
    }

    STAGE(0, 0);

    for (int kt = 0; kt < NT; ++kt) {
        const int b = kt & 1;
        __syncthreads();                    // K staging of buf b complete

        // V fragments for THIS tile straight from global (L2-hit); issued
        // first so they are oldest in the vmem queue -- the wait before PV
        // leaves the K-prefetch below still in flight.
        bf16x8 vf[2][4];
        #pragma unroll
        for (int ks = 0; ks < 4; ++ks) {
            vf[0][ks] = *(const bf16x8*)(Vrow0 + kt * 64 + ks * 16);
            vf[1][ks] = *(const bf16x8*)(Vrow1 + kt * 64 + ks * 16);
        }

        if (kt + 1 < NT) STAGE(b ^ 1, kt + 1);  // K prefetch for next tile

        // --- QK^T (swapped): S^T[k][q] per 32-key subtile, then softmax ---
        u32x4 pa[4];     // PV A-fragments, k-subtiles of 16
        #pragma unroll
        for (int s = 0; s < 2; ++s) {
            f32x16 sacc;
            #pragma unroll
            for (int r = 0; r < 16; ++r) sacc[r] = 0.f;
            #pragma unroll
            for (int c = 0; c < 4; ++c) {
                // A-operand: row k = 32s + l31, contraction d = 16c + 8hi + j
                bf16x8 kf = *(const bf16x8*)(
                    &Ks[b][(32 * s + l31) * 64 + (((c << 1) | hi) ^ m7) * 8]);
                sacc = __builtin_amdgcn_mfma_f32_32x32x16_bf16(
                    kf, qf[c], sacc, 0, 0, 0);
            }
            // lane holds S^T[k = (r&3)+8*(r>>2)+4hi + 32s][q = l31]
            float p[16];
            #pragma unroll
            for (int r = 0; r < 16; ++r) {
                p[r] = fast_exp2(sacc[r]);
                l4[r & 3] += p[r];
            }
            unsigned x[8];
            #pragma unroll
            for (int i = 0; i < 8; ++i)
                x[i] = cvt_pk_bf16(p[2 * i], p[2 * i + 1]);
            // exchange k-halves between lane and lane^32 (same q)
            swap32(x[0], x[2]); swap32(x[1], x[3]);
            swap32(x[4], x[6]); swap32(x[5], x[7]);
            pa[2 * s][0] = x[0]; pa[2 * s][1] = x[1];
            pa[2 * s][2] = x[2]; pa[2 * s][3] = x[3];
            pa[2 * s + 1][0] = x[4]; pa[2 * s + 1][1] = x[5];
            pa[2 * s + 1][2] = x[6]; pa[2 * s + 1][3] = x[7];
        }

        // --- PV: O[q][d] += P[q][k] V[k][d], 4 k-subtiles x 2 d-tiles ---
        #pragma unroll
        for (int dt = 0; dt < 2; ++dt)
            #pragma unroll
            for (int ks = 0; ks < 4; ++ks)
                Oacc[dt] = __builtin_amdgcn_mfma_f32_32x32x16_bf16(
                    as_bf16x8(pa[ks]), vf[dt][ks], Oacc[dt], 0, 0, 0);
    }
#undef STAGE

    // l: lane and lane^32 hold complementary k-halves of the same q; build
    // per-wave inv-l broadcast table (acc rows need OTHER lanes' q values)
    {
        float v = (l4[0] + l4[1]) + (l4[2] + l4[3]);
        v += __shfl_xor(v, 32);
        if (hi == 0)
            Linv[wave][l31] = 1.f / v;
    }
    __syncthreads();

    // normalized O, bf16, [bh][t][d] flat -- final output of attention
    const size_t base = ((size_t)bh * TSEQ + q0) * HDIM;
    #pragma unroll
    for (int dt = 0; dt < 2; ++dt)
        #pragma unroll
        for (int r = 0; r < 16; ++r) {
            const int ql = (r & 3) + 8 * (r >> 2) + 4 * hi;
            const float inv = Linv[wave][ql];   // same addr across l31: bcast
            Ob[base + (size_t)ql * HDIM + dt * 32 + l31] =
                (__bf16)(Oacc[dt][r] * inv);
        }
}

// ---------------------------------------------------------------------------
// bf16 MFMA GEMM for out-projection, BM=128 BN=64 BK=64: per wave 64x32
// output (4x2 of 16x16), 16 MFMA : 12 ds_read per K-step, barrier amortized
// 2x. grid (16, 32) = 512 blocks = 2/CU, LDS 24KB. Epilogue +bias, fp32.
// ---------------------------------------------------------------------------
__global__ __launch_bounds__(256) void gemm_out_kernel(
    const __bf16* __restrict__ A, const __bf16* __restrict__ BT,
    const float* __restrict__ bias, float* __restrict__ out)
{
    __shared__ __align__(16) __bf16 As[128 * 64];
    __shared__ __align__(16) __bf16 Bs[64 * 64];
    const int tid = threadIdx.x;
    const int wave = tid >> 6, lane = tid & 63;
    const int l16 = lane & 15, quad = lane >> 4;
    const int wm = wave >> 1, wn = wave & 1;
    const int m0 = blockIdx.y * 128, n0 = blockIdx.x * 64;

    f32x4 acc[4][2];
    #pragma unroll
    for (int mt = 0; mt < 4; ++mt)
        #pragma unroll
        for (int nt = 0; nt < 2; ++nt)
            #pragma unroll
            for (int r = 0; r < 4; ++r) acc[mt][nt][r] = 0.f;

    // A staging: 4 chunks/thread covering 128 rows
    int amrow[4], amchk[4], ambase[4];
    #pragma unroll
    for (int i = 0; i < 4; ++i) {
        int linear = (wave * 4 + i) * 64 + lane;
        amrow[i] = linear >> 3;
        amchk[i] = (linear & 7) ^ (amrow[i] & 7);
        ambase[i] = (wave * 4 + i) * 512;
    }
    // B staging: 2 chunks/thread covering 64 rows
    int brow[2], bchk[2], bbase[2];
    #pragma unroll
    for (int i = 0; i < 2; ++i) {
        const int s = wave * 2 + i;
        brow[i] = s * 8 + (lane >> 3);
        bchk[i] = (lane & 7) ^ (brow[i] & 7);
        bbase[i] = s * 512;
    }

    for (int k0 = 0; k0 < 1024; k0 += 64) {
        #pragma unroll
        for (int i = 0; i < 4; ++i)
            gload_lds16(A + (size_t)(m0 + amrow[i]) * 1024 + k0 + amchk[i] * 8,
                        As + ambase[i]);
        #pragma unroll
        for (int i = 0; i < 2; ++i)
            gload_lds16(BT + (size_t)(n0 + brow[i]) * 1024 + k0 + bchk[i] * 8,
                        Bs + bbase[i]);
        __syncthreads();
        #pragma unroll
        for (int kk = 0; kk < 2; ++kk) {
            bf16x8 am[4], bn[2];
            #pragma unroll
            for (int mt = 0; mt < 4; ++mt) {
                int row = wm * 64 + mt * 16 + l16;
                int c = (kk * 4 + quad) ^ (row & 7);
                am[mt] = *(const bf16x8*)(As + row * 64 + c * 8);
            }
            #pragma unroll
            for (int nt = 0; nt < 2; ++nt) {
                int row = wn * 32 + nt * 16 + l16;
                int c = (kk * 4 + quad) ^ (row & 7);
                bn[nt] = *(const bf16x8*)(Bs + row * 64 + c * 8);
            }
            #pragma unroll
            for (int mt = 0; mt < 4; ++mt)
                #pragma unroll
                for (int nt = 0; nt < 2; ++nt)
                    acc[mt][nt] = __builtin_amdgcn_mfma_f32_16x16x32_bf16(
                        am[mt], bn[nt], acc[mt][nt], 0, 0, 0);
        }
        __syncthreads();
    }

    #pragma unroll
    for (int nt = 0; nt < 2; ++nt) {
        const int col = n0 + wn * 32 + nt * 16 + l16;
        const float bv = bias[col];
        #pragma unroll
        for (int mt = 0; mt < 4; ++mt)
            #pragma unroll
            for (int r = 0; r < 4; ++r) {
                const int row = m0 + wm * 64 + mt * 16 + quad * 4 + r;
                out[(size_t)row * 1024 + col] = acc[mt][nt][r] + bv;
            }
    }
}

// ---------------------------------------------------------------------------
extern "C" void kernel_launch(void* const* d_in, const int* in_sizes, int n_in,
                              void* d_out, int out_size, void* d_ws, size_t ws_size,
                              hipStream_t stream) {
    const float* x     = (const float*)d_in[0];   // (2048, 2, 1024)
    const float* w_in  = (const float*)d_in[1];   // (1024, 3072)
    const float* b_in  = (const float*)d_in[2];   // (3072,)
    const float* w_out = (const float*)d_in[3];   // (1024, 1024)
    const float* b_out = (const float*)d_in[4];   // (1024,)
    float* out = (float*)d_out;                   // (2, 2048, 1024) flat 4096x1024

    const size_t M1 = (size_t)1024 * 1024;
    __bf16* ws  = (__bf16*)d_ws;
    __bf16* xb  = ws;                 // 4M elem
    __bf16* wiT = xb  + 4 * M1;       // 3M
    __bf16* whT = wiT + 3 * M1;       // 1M
    __bf16* Qb  = whT + 1 * M1;       // 4M
    __bf16* Kb  = Qb  + 4 * M1;       // 4M
    __bf16* Vt  = Kb  + 4 * M1;       // 4M  (written transposed by gemm_qkv)
    __bf16* Ob  = xb;                 // alias: xb dead after gemm_qkv

    prep_kernel<<<8192, 256, 0, stream>>>(x, w_in, w_out, xb, wiT, whT);
    gemm_qkv_kernel<<<dim3(24, 32), 256, 0, stream>>>(
        xb, wiT, b_in, Qb, Kb, Vt);
    attn_mfma_kernel<<<dim3(512), 256, 0, stream>>>(
        Qb, Kb, Vt, Ob);
    gemm_out_kernel<<<dim3(16, 32), 256, 0, stream>>>(
        Ob, whT, b_out, out);
}

// Round 10
// 184.836 us; speedup vs baseline: 1.1818x; 1.1818x over previous
//
#include <hip/hip_runtime.h>
#include <stdint.h>

#define TSEQ 2048
#define NB 2
#define EMB 1024
#define NHEAD 16
#define HDIM 64
#define NT (TSEQ / 64)            // 32 key-tiles per block (full softmax)
// 0.125 (D^-0.5) * log2(e), folded into Q at the in-proj epilogue
#define QSCALE 0.18033688f

typedef __bf16 bf16x8 __attribute__((ext_vector_type(8)));
typedef __bf16 bf16x4 __attribute__((ext_vector_type(4)));
typedef float f32x4 __attribute__((ext_vector_type(4)));
typedef float f32x16 __attribute__((ext_vector_type(16)));
typedef unsigned int u32x4 __attribute__((ext_vector_type(4)));

// async 16B global->LDS. lds base must be wave-uniform; HW scatters lane*16.
__device__ __forceinline__ void gload_lds16(const void* g, void* lds) {
    __builtin_amdgcn_global_load_lds(
        (const __attribute__((address_space(1))) unsigned int*)g,
        (__attribute__((address_space(3))) unsigned int*)lds, 16, 0, 0);
}

__device__ __forceinline__ float fast_exp2(float x) {
#if __has_builtin(__builtin_amdgcn_exp2f)
    return __builtin_amdgcn_exp2f(x);   // raw v_exp_f32; inputs bounded
#else
    return exp2f(x);
#endif
}

// packed f32 pair -> bf16x2 in one u32 (lo in [15:0], hi in [31:16])
__device__ __forceinline__ unsigned cvt_pk_bf16(float lo, float hi) {
    unsigned r;
    asm("v_cvt_pk_bf16_f32 %0, %1, %2" : "=v"(r) : "v"(lo), "v"(hi));
    return r;
}

// a[32:63] <-> b[0:31]
__device__ __forceinline__ void swap32(unsigned& a, unsigned& b) {
    asm("v_permlane32_swap_b32 %0, %1" : "+v"(a), "+v"(b));
}

__device__ __forceinline__ bf16x8 as_bf16x8(u32x4 u) {
    union { u32x4 u; bf16x8 h; } c;
    c.u = u;
    return c.h;
}

// ---------------------------------------------------------------------------
// merged prep: bid<4096 -> cvt x (4096x1024 f32 -> bf16);
// else transpose+cvt weights f32 [1024][sn] -> bf16 [sn][1024].
// grid 4096 + 128*32 = 8192, block 256.
// ---------------------------------------------------------------------------
__global__ __launch_bounds__(256) void prep_kernel(
    const float* __restrict__ x, const float* __restrict__ w_in,
    const float* __restrict__ w_out,
    __bf16* __restrict__ xb, __bf16* __restrict__ wiT, __bf16* __restrict__ whT)
{
    __shared__ float tile[32][33];
    int bid = blockIdx.x;
    const int tid = threadIdx.x;
    if (bid < 4096) {
        const size_t idx = ((size_t)bid * 256 + tid) * 4;
        float4 v = *(const float4*)(x + idx);
        bf16x4 o = { (__bf16)v.x, (__bf16)v.y, (__bf16)v.z, (__bf16)v.w };
        *(bf16x4*)(xb + idx) = o;
        return;
    }
    bid -= 4096;
    int bx = bid & 127;            // 0..127
    const int by = bid >> 7;       // 0..31
    const float* src; __bf16* dst; int sn;
    if (bx < 96) { src = w_in;  dst = wiT; sn = 3072; }
    else         { bx -= 96; src = w_out; dst = whT; sn = 1024; }
    const int tx = tid & 31, ty = tid >> 5;
    #pragma unroll
    for (int i = 0; i < 4; ++i)
        tile[ty + i * 8][tx] = src[(size_t)(by * 32 + ty + i * 8) * sn + bx * 32 + tx];
    __syncthreads();
    #pragma unroll
    for (int i = 0; i < 4; ++i) {
        float v = tile[tx][ty + i * 8];
        dst[(size_t)(bx * 32 + ty + i * 8) * 1024 + by * 32 + tx] = (__bf16)v;
    }
}

// ---------------------------------------------------------------------------
// bf16 MFMA GEMM for in-projection. 128x128 tile, BK=64. Flat 768-block grid
// with XCD-chunked decode (768%8==0, bijective): XCD c owns an 8m x 12n
// super-tile -> per-XCD L2 working set 8*256KB(A) + 12*256KB(B) = 5MB,
// cutting cross-XCD panel re-fetch (~112MB -> ~40MB). sec = n0>>10 is
// block-uniform. Q (pre-scaled) / K stored [bh][t][d]; V via LDS transpose
// (overlay, stride 131) -> Vt [bh][d][t] directly. LDS 33.5KB.
// ---------------------------------------------------------------------------
__global__ __launch_bounds__(256) void gemm_qkv_kernel(
    const __bf16* __restrict__ A, const __bf16* __restrict__ BT,
    const float* __restrict__ bias,
    __bf16* __restrict__ Oq, __bf16* __restrict__ Ok, __bf16* __restrict__ Vt)
{
    __shared__ __align__(16) char smem[128 * 131 * 2];  // 33536B
    __bf16* As = (__bf16*)smem;              // 128x64, main loop
    __bf16* Bs = (__bf16*)(smem + 16384);    // 128x64, main loop
    __bf16* Tt = (__bf16*)smem;              // 128x131, V epilogue (overlay)

    const int tid = threadIdx.x;
    const int wave = tid >> 6, lane = tid & 63;
    const int l16 = lane & 15, quad = lane >> 4;
    const int wm = wave >> 1, wn = wave & 1;

    // XCD-chunked decode: hardware XCD = blockIdx.x % 8. XCD c covers
    // m-panels (c&3)*8 + [0,8) x n-panels (c>>2)*12 + [0,12).
    const int lid = blockIdx.x;          // 0..767
    const int xcd = lid & 7;
    const int j   = lid >> 3;            // 0..95
    const int m0 = ((xcd & 3) * 8 + j / 12) * 128;
    const int n0 = ((xcd >> 2) * 12 + j % 12) * 128;

    f32x4 acc[4][4];
    #pragma unroll
    for (int mt = 0; mt < 4; ++mt)
        #pragma unroll
        for (int nt = 0; nt < 4; ++nt)
            #pragma unroll
            for (int r = 0; r < 4; ++r) acc[mt][nt][r] = 0.f;

    int smrow[4], schunk[4], sbase[4];
    #pragma unroll
    for (int i = 0; i < 4; ++i) {
        int linear = (wave * 4 + i) * 64 + lane;
        smrow[i] = linear >> 3;
        schunk[i] = (linear & 7) ^ (smrow[i] & 7);
        sbase[i] = (wave * 4 + i) * 512;
    }

    for (int k0 = 0; k0 < 1024; k0 += 64) {
        #pragma unroll
        for (int i = 0; i < 4; ++i) {
            gload_lds16(A + (size_t)(m0 + smrow[i]) * 1024 + k0 + schunk[i] * 8,
                        As + sbase[i]);
            gload_lds16(BT + (size_t)(n0 + smrow[i]) * 1024 + k0 + schunk[i] * 8,
                        Bs + sbase[i]);
        }
        __syncthreads();
        #pragma unroll
        for (int kk = 0; kk < 2; ++kk) {
            bf16x8 am[4], bn[4];
            #pragma unroll
            for (int mt = 0; mt < 4; ++mt) {
                int row = wm * 64 + mt * 16 + l16;
                int c = (kk * 4 + quad) ^ (row & 7);
                am[mt] = *(const bf16x8*)(As + row * 64 + c * 8);
            }
            #pragma unroll
            for (int nt = 0; nt < 4; ++nt) {
                int row = wn * 64 + nt * 16 + l16;
                int c = (kk * 4 + quad) ^ (row & 7);
                bn[nt] = *(const bf16x8*)(Bs + row * 64 + c * 8);
            }
            #pragma unroll
            for (int mt = 0; mt < 4; ++mt)
                #pragma unroll
                for (int nt = 0; nt < 4; ++nt)
                    acc[mt][nt] = __builtin_amdgcn_mfma_f32_16x16x32_bf16(
                        am[mt], bn[nt], acc[mt][nt], 0, 0, 0);
        }
        __syncthreads();
    }

    const int sec = n0 >> 10;                // block-uniform: 0=Q, 1=K, 2=V
    if (sec < 2) {
        __bf16* __restrict__ O = (sec == 0) ? Oq : Ok;
        const float scale = (sec == 0) ? QSCALE : 1.f;
        #pragma unroll
        for (int nt = 0; nt < 4; ++nt) {
            const int col = n0 + wn * 64 + nt * 16 + l16;
            const float bv = bias[col];
            const int f = col & 1023;
            const int h = f >> 6, d = f & 63;
            #pragma unroll
            for (int mt = 0; mt < 4; ++mt)
                #pragma unroll
                for (int r = 0; r < 4; ++r) {
                    const int row = m0 + wm * 64 + mt * 16 + quad * 4 + r;
                    const float v = (acc[mt][nt][r] + bv) * scale;
                    const int t = row >> 1, b = row & 1;
                    const int bh = b * NHEAD + h;
                    O[((size_t)bh * TSEQ + t) * HDIM + d] = (__bf16)v;
                }
        }
    } else {
        // V: acc -> LDS (stride 131, odd -> transpose reads 2-way max),
        // barrier, transposed coalesced store to Vt [bh][d][t]
        #pragma unroll
        for (int nt = 0; nt < 4; ++nt) {
            const int lc = wn * 64 + nt * 16 + l16;
            const float bv = bias[n0 + lc];
            #pragma unroll
            for (int mt = 0; mt < 4; ++mt)
                #pragma unroll
                for (int r = 0; r < 4; ++r) {
                    const int ml = wm * 64 + mt * 16 + quad * 4 + r;
                    Tt[ml * 131 + lc] = (__bf16)(acc[mt][nt][r] + bv);
                }
        }
        __syncthreads();
        // wave -> (b, h_local); rows ml = 2*t_local + b, cols lc = hl*64 + d
        const int b = wave & 1, hl = wave >> 1;
        const int bh = b * NHEAD + ((n0 - 2048) >> 6) + hl;
        const int t0g = m0 >> 1;
        __bf16* dstbase = Vt + (size_t)bh * HDIM * TSEQ + t0g;
        const int dq = lane >> 3;          // d low bits 0..7
        const int tb = (lane & 7) * 8;     // t chunk base
        #pragma unroll
        for (int p = 0; p < 8; ++p) {
            const int d = dq + 8 * p;
            bf16x8 o;
            #pragma unroll
            for (int jj = 0; jj < 8; ++jj)
                o[jj] = Tt[(2 * (tb + jj) + b) * 131 + hl * 64 + d];
            *(bf16x8*)(dstbase + (size_t)d * TSEQ + tb) = o;
        }
    }
}

// ---------------------------------------------------------------------------
// MFMA flash attention v12 (R8-proven, 50.5us): fused-normalize, full
// 2048-key softmax, 4 waves x 32 q, grid 512 = 2 blocks/CU, swapped 32x32x16
// QK^T + in-register softmax (cvt_pk + permlane32_swap), Ks/Vs double-
// buffered gload_lds staging (the staging IS the coalescing transform --
// R9 showed per-lane direct V reads are 4KB-strided and cost +65%).
// LDS 32.5KB, VGPR ~68.
// ---------------------------------------------------------------------------
__global__ __launch_bounds__(256, 2) void attn_mfma_kernel(
    const __bf16* __restrict__ Q, const __bf16* __restrict__ K,
    const __bf16* __restrict__ Vt, __bf16* __restrict__ Ob)
{
    __shared__ __align__(16) __bf16 Ks[2][64 * 64];     // 16KB
    __shared__ __align__(16) __bf16 Vs[2][64 * 64];     // 16KB
    __shared__ float Linv[4][32];                       // 512B

    const int tid  = threadIdx.x;
    const int wave = tid >> 6;
    const int lane = tid & 63;
    const int l31  = lane & 31;
    const int hi   = lane >> 5;
    const int m7   = l31 & 7;

    // XCD-aware decode: hardware assigns XCD = blockIdx.x % 8 (round-robin).
    const int lid = blockIdx.x;        // 0..511
    const int xcd = lid & 7;
    const int j   = lid >> 3;          // 0..63 within XCD
    const int bh  = xcd * 4 + (j >> 4);    // 0..31
    const int qb  = j & 15;            // q-tile 0..15

    const int q0 = qb * 128 + wave * 32;

    // Q fragments (B-operand): col = q = l31, contraction d = 16c + 8hi + j
    bf16x8 qf[4];
    {
        const __bf16* Qrow = Q + ((size_t)bh * TSEQ + q0 + l31) * HDIM + 8 * hi;
        #pragma unroll
        for (int c = 0; c < 4; ++c)
            qf[c] = *(const bf16x8*)(Qrow + 16 * c);
    }

    // O accumulators: per d-tile dt, lane holds col d = 32*dt + l31,
    // rows q = (r&3) + 8*(r>>2) + 4*hi
    f32x16 Oacc[2];
    #pragma unroll
    for (int dt = 0; dt < 2; ++dt)
        #pragma unroll
        for (int r = 0; r < 16; ++r) Oacc[dt][r] = 0.f;
    float l4[4] = {0.f, 0.f, 0.f, 0.f};

    const __bf16* Kbase = K + (size_t)bh * TSEQ * HDIM;
    const __bf16* Vbase = Vt + (size_t)bh * HDIM * TSEQ;

    int srow[2], schk[2];
    #pragma unroll
    for (int i = 0; i < 2; ++i) {
        const int s = wave * 2 + i;
        srow[i] = s * 8 + (lane >> 3);
        schk[i] = (lane & 7) ^ (srow[i] & 7);
    }

#define STAGE(buf, kt)                                                        \
    {                                                                         \
        _Pragma("unroll")                                                     \
        for (int i = 0; i < 2; ++i) {                                         \
            const int s = wave * 2 + i;                                       \
            gload_lds16(Kbase + (size_t)((kt) * 64 + srow[i]) * HDIM          \
                            + schk[i] * 8,                                    \
                        &Ks[buf][s * 512]);                                   \
            gload_lds16(Vbase + (size_t)srow[i] * TSEQ + (kt) * 64            \
                            + schk[i] * 8,                                    \
                        &Vs[buf][s * 512]);                                   \
        }                                                                     \
    }

    STAGE(0, 0);

    for (int kt = 0; kt < NT; ++kt) {
        const int b = kt & 1;
        __syncthreads();                    // staging of buf b complete
        if (kt + 1 < NT) STAGE(b ^ 1, kt + 1);  // overlap next-tile loads

        // --- QK^T (swapped): S^T[k][q] per 32-key subtile, then softmax ---
        u32x4 pa[4];     // PV A-fragments, k-subtiles of 16
        #pragma unroll
        for (int s = 0; s < 2; ++s) {
            f32x16 sacc;
            #pragma unroll
            for (int r = 0; r < 16; ++r) sacc[r] = 0.f;
            #pragma unroll
            for (int c = 0; c < 4; ++c) {
                // A-operand: row k = 32s + l31, contraction d = 16c + 8hi + j
                bf16x8 kf = *(const bf16x8*)(
                    &Ks[b][(32 * s + l31) * 64 + (((c << 1) | hi) ^ m7) * 8]);
                sacc = __builtin_amdgcn_mfma_f32_32x32x16_bf16(
                    kf, qf[c], sacc, 0, 0, 0);
            }
            // lane holds S^T[k = (r&3)+8*(r>>2)+4hi + 32s][q = l31]
            float p[16];
            #pragma unroll
            for (int r = 0; r < 16; ++r) {
                p[r] = fast_exp2(sacc[r]);
                l4[r & 3] += p[r];
            }
            unsigned x[8];
            #pragma unroll
            for (int i = 0; i < 8; ++i)
                x[i] = cvt_pk_bf16(p[2 * i], p[2 * i + 1]);
            // exchange k-halves between lane and lane^32 (same q)
            swap32(x[0], x[2]); swap32(x[1], x[3]);
            swap32(x[4], x[6]); swap32(x[5], x[7]);
            pa[2 * s][0] = x[0]; pa[2 * s][1] = x[1];
            pa[2 * s][2] = x[2]; pa[2 * s][3] = x[3];
            pa[2 * s + 1][0] = x[4]; pa[2 * s + 1][1] = x[5];
            pa[2 * s + 1][2] = x[6]; pa[2 * s + 1][3] = x[7];
        }

        // --- PV: O[q][d] += P[q][k] V[k][d], 4 k-subtiles x 2 d-tiles ---
        #pragma unroll
        for (int dt = 0; dt < 2; ++dt)
            #pragma unroll
            for (int ks = 0; ks < 4; ++ks) {
                // B-operand: col d = 32dt + l31, contraction k' = 8hi + j
                bf16x8 vf = *(const bf16x8*)(
                    &Vs[b][(dt * 32 + l31) * 64 + (((ks << 1) | hi) ^ m7) * 8]);
                Oacc[dt] = __builtin_amdgcn_mfma_f32_32x32x16_bf16(
                    as_bf16x8(pa[ks]), vf, Oacc[dt], 0, 0, 0);
            }
    }
#undef STAGE

    // l: lane and lane^32 hold complementary k-halves of the same q; build
    // per-wave inv-l broadcast table (acc rows need OTHER lanes' q values)
    {
        float v = (l4[0] + l4[1]) + (l4[2] + l4[3]);
        v += __shfl_xor(v, 32);
        if (hi == 0)
            Linv[wave][l31] = 1.f / v;
    }
    __syncthreads();

    // normalized O, bf16, [bh][t][d] flat -- final output of attention
    const size_t base = ((size_t)bh * TSEQ + q0) * HDIM;
    #pragma unroll
    for (int dt = 0; dt < 2; ++dt)
        #pragma unroll
        for (int r = 0; r < 16; ++r) {
            const int ql = (r & 3) + 8 * (r >> 2) + 4 * hi;
            const float inv = Linv[wave][ql];   // same addr across l31: bcast
            Ob[base + (size_t)ql * HDIM + dt * 32 + l31] =
                (__bf16)(Oacc[dt][r] * inv);
        }
}

// ---------------------------------------------------------------------------
// bf16 MFMA GEMM for out-projection, BM=128 BN=64 BK=64: per wave 64x32
// output (4x2 of 16x16), 16 MFMA : 12 ds_read per K-step, barrier amortized
// 2x. grid (16, 32) = 512 blocks = 2/CU, LDS 24KB. Epilogue +bias, fp32.
// ---------------------------------------------------------------------------
__global__ __launch_bounds__(256) void gemm_out_kernel(
    const __bf16* __restrict__ A, const __bf16* __restrict__ BT,
    const float* __restrict__ bias, float* __restrict__ out)
{
    __shared__ __align__(16) __bf16 As[128 * 64];
    __shared__ __align__(16) __bf16 Bs[64 * 64];
    const int tid = threadIdx.x;
    const int wave = tid >> 6, lane = tid & 63;
    const int l16 = lane & 15, quad = lane >> 4;
    const int wm = wave >> 1, wn = wave & 1;
    const int m0 = blockIdx.y * 128, n0 = blockIdx.x * 64;

    f32x4 acc[4][2];
    #pragma unroll
    for (int mt = 0; mt < 4; ++mt)
        #pragma unroll
        for (int nt = 0; nt < 2; ++nt)
            #pragma unroll
            for (int r = 0; r < 4; ++r) acc[mt][nt][r] = 0.f;

    // A staging: 4 chunks/thread covering 128 rows
    int amrow[4], amchk[4], ambase[4];
    #pragma unroll
    for (int i = 0; i < 4; ++i) {
        int linear = (wave * 4 + i) * 64 + lane;
        amrow[i] = linear >> 3;
        amchk[i] = (linear & 7) ^ (amrow[i] & 7);
        ambase[i] = (wave * 4 + i) * 512;
    }
    // B staging: 2 chunks/thread covering 64 rows
    int brow[2], bchk[2], bbase[2];
    #pragma unroll
    for (int i = 0; i < 2; ++i) {
        const int s = wave * 2 + i;
        brow[i] = s * 8 + (lane >> 3);
        bchk[i] = (lane & 7) ^ (brow[i] & 7);
        bbase[i] = s * 512;
    }

    for (int k0 = 0; k0 < 1024; k0 += 64) {
        #pragma unroll
        for (int i = 0; i < 4; ++i)
            gload_lds16(A + (size_t)(m0 + amrow[i]) * 1024 + k0 + amchk[i] * 8,
                        As + ambase[i]);
        #pragma unroll
        for (int i = 0; i < 2; ++i)
            gload_lds16(BT + (size_t)(n0 + brow[i]) * 1024 + k0 + bchk[i] * 8,
                        Bs + bbase[i]);
        __syncthreads();
        #pragma unroll
        for (int kk = 0; kk < 2; ++kk) {
            bf16x8 am[4], bn[2];
            #pragma unroll
            for (int mt = 0; mt < 4; ++mt) {
                int row = wm * 64 + mt * 16 + l16;
                int c = (kk * 4 + quad) ^ (row & 7);
                am[mt] = *(const bf16x8*)(As + row * 64 + c * 8);
            }
            #pragma unroll
            for (int nt = 0; nt < 2; ++nt) {
                int row = wn * 32 + nt * 16 + l16;
                int c = (kk * 4 + quad) ^ (row & 7);
                bn[nt] = *(const bf16x8*)(Bs + row * 64 + c * 8);
            }
            #pragma unroll
            for (int mt = 0; mt < 4; ++mt)
                #pragma unroll
                for (int nt = 0; nt < 2; ++nt)
                    acc[mt][nt] = __builtin_amdgcn_mfma_f32_16x16x32_bf16(
                        am[mt], bn[nt], acc[mt][nt], 0, 0, 0);
        }
        __syncthreads();
    }

    #pragma unroll
    for (int nt = 0; nt < 2; ++nt) {
        const int col = n0 + wn * 32 + nt * 16 + l16;
        const float bv = bias[col];
        #pragma unroll
        for (int mt = 0; mt < 4; ++mt)
            #pragma unroll
            for (int r = 0; r < 4; ++r) {
                const int row = m0 + wm * 64 + mt * 16 + quad * 4 + r;
                out[(size_t)row * 1024 + col] = acc[mt][nt][r] + bv;
            }
    }
}

// ---------------------------------------------------------------------------
extern "C" void kernel_launch(void* const* d_in, const int* in_sizes, int n_in,
                              void* d_out, int out_size, void* d_ws, size_t ws_size,
                              hipStream_t stream) {
    const float* x     = (const float*)d_in[0];   // (2048, 2, 1024)
    const float* w_in  = (const float*)d_in[1];   // (1024, 3072)
    const float* b_in  = (const float*)d_in[2];   // (3072,)
    const float* w_out = (const float*)d_in[3];   // (1024, 1024)
    const float* b_out = (const float*)d_in[4];   // (1024,)
    float* out = (float*)d_out;                   // (2, 2048, 1024) flat 4096x1024

    const size_t M1 = (size_t)1024 * 1024;
    __bf16* ws  = (__bf16*)d_ws;
    __bf16* xb  = ws;                 // 4M elem
    __bf16* wiT = xb  + 4 * M1;       // 3M
    __bf16* whT = wiT + 3 * M1;       // 1M
    __bf16* Qb  = whT + 1 * M1;       // 4M
    __bf16* Kb  = Qb  + 4 * M1;       // 4M
    __bf16* Vt  = Kb  + 4 * M1;       // 4M  (written transposed by gemm_qkv)
    __bf16* Ob  = xb;                 // alias: xb dead after gemm_qkv

    prep_kernel<<<8192, 256, 0, stream>>>(x, w_in, w_out, xb, wiT, whT);
    gemm_qkv_kernel<<<dim3(768), 256, 0, stream>>>(
        xb, wiT, b_in, Qb, Kb, Vt);
    attn_mfma_kernel<<<dim3(512), 256, 0, stream>>>(
        Qb, Kb, Vt, Ob);
    gemm_out_kernel<<<dim3(16, 32), 256, 0, stream>>>(
        Ob, whT, b_out, out);
}

// Round 11
// 182.723 us; speedup vs baseline: 1.1955x; 1.0116x over previous
//
#include <hip/hip_runtime.h>
#include <stdint.h>

#define TSEQ 2048
#define NB 2
#define EMB 1024
#define NHEAD 16
#define HDIM 64
#define NT (TSEQ / 64)            // 32 key-tiles per block (full softmax)
// 0.125 (D^-0.5) * log2(e), folded into Q at the in-proj epilogue
#define QSCALE 0.18033688f

typedef __bf16 bf16x8 __attribute__((ext_vector_type(8)));
typedef __bf16 bf16x4 __attribute__((ext_vector_type(4)));
typedef float f32x4 __attribute__((ext_vector_type(4)));
typedef float f32x16 __attribute__((ext_vector_type(16)));
typedef unsigned int u32x4 __attribute__((ext_vector_type(4)));

// async 16B global->LDS. lds base must be wave-uniform; HW scatters lane*16.
__device__ __forceinline__ void gload_lds16(const void* g, void* lds) {
    __builtin_amdgcn_global_load_lds(
        (const __attribute__((address_space(1))) unsigned int*)g,
        (__attribute__((address_space(3))) unsigned int*)lds, 16, 0, 0);
}

__device__ __forceinline__ float fast_exp2(float x) {
#if __has_builtin(__builtin_amdgcn_exp2f)
    return __builtin_amdgcn_exp2f(x);   // raw v_exp_f32; inputs bounded
#else
    return exp2f(x);
#endif
}

// packed f32 pair -> bf16x2 in one u32 (lo in [15:0], hi in [31:16])
__device__ __forceinline__ unsigned cvt_pk_bf16(float lo, float hi) {
    unsigned r;
    asm("v_cvt_pk_bf16_f32 %0, %1, %2" : "=v"(r) : "v"(lo), "v"(hi));
    return r;
}

// a[32:63] <-> b[0:31]
__device__ __forceinline__ void swap32(unsigned& a, unsigned& b) {
    asm("v_permlane32_swap_b32 %0, %1" : "+v"(a), "+v"(b));
}

__device__ __forceinline__ bf16x8 as_bf16x8(u32x4 u) {
    union { u32x4 u; bf16x8 h; } c;
    c.u = u;
    return c.h;
}

// ---------------------------------------------------------------------------
// merged prep: bid<4096 -> cvt x (4096x1024 f32 -> bf16);
// else transpose+cvt weights f32 [1024][sn] -> bf16 [sn][1024].
// grid 4096 + 128*32 = 8192, block 256.
// ---------------------------------------------------------------------------
__global__ __launch_bounds__(256) void prep_kernel(
    const float* __restrict__ x, const float* __restrict__ w_in,
    const float* __restrict__ w_out,
    __bf16* __restrict__ xb, __bf16* __restrict__ wiT, __bf16* __restrict__ whT)
{
    __shared__ float tile[32][33];
    int bid = blockIdx.x;
    const int tid = threadIdx.x;
    if (bid < 4096) {
        const size_t idx = ((size_t)bid * 256 + tid) * 4;
        float4 v = *(const float4*)(x + idx);
        bf16x4 o = { (__bf16)v.x, (__bf16)v.y, (__bf16)v.z, (__bf16)v.w };
        *(bf16x4*)(xb + idx) = o;
        return;
    }
    bid -= 4096;
    int bx = bid & 127;            // 0..127
    const int by = bid >> 7;       // 0..31
    const float* src; __bf16* dst; int sn;
    if (bx < 96) { src = w_in;  dst = wiT; sn = 3072; }
    else         { bx -= 96; src = w_out; dst = whT; sn = 1024; }
    const int tx = tid & 31, ty = tid >> 5;
    #pragma unroll
    for (int i = 0; i < 4; ++i)
        tile[ty + i * 8][tx] = src[(size_t)(by * 32 + ty + i * 8) * sn + bx * 32 + tx];
    __syncthreads();
    #pragma unroll
    for (int i = 0; i < 4; ++i) {
        float v = tile[tx][ty + i * 8];
        dst[(size_t)(bx * 32 + ty + i * 8) * 1024 + by * 32 + tx] = (__bf16)v;
    }
}

// ---------------------------------------------------------------------------
// bf16 MFMA GEMM for in-projection. 128x128 tile, BK=64. R8-proven grid
// (24, 32) restored (R10's XCD-chunked flat grid regressed this kernel to
// 58.6us). sec = n0>>10 is block-uniform. Q (pre-scaled) / K stored
// [bh][t][d]; V via LDS transpose (overlay, stride 131) -> Vt [bh][d][t]
// directly. LDS 33.5KB.
// ---------------------------------------------------------------------------
__global__ __launch_bounds__(256) void gemm_qkv_kernel(
    const __bf16* __restrict__ A, const __bf16* __restrict__ BT,
    const float* __restrict__ bias,
    __bf16* __restrict__ Oq, __bf16* __restrict__ Ok, __bf16* __restrict__ Vt)
{
    __shared__ __align__(16) char smem[128 * 131 * 2];  // 33536B
    __bf16* As = (__bf16*)smem;              // 128x64, main loop
    __bf16* Bs = (__bf16*)(smem + 16384);    // 128x64, main loop
    __bf16* Tt = (__bf16*)smem;              // 128x131, V epilogue (overlay)

    const int tid = threadIdx.x;
    const int wave = tid >> 6, lane = tid & 63;
    const int l16 = lane & 15, quad = lane >> 4;
    const int wm = wave >> 1, wn = wave & 1;
    const int m0 = blockIdx.y * 128, n0 = blockIdx.x * 128;

    f32x4 acc[4][4];
    #pragma unroll
    for (int mt = 0; mt < 4; ++mt)
        #pragma unroll
        for (int nt = 0; nt < 4; ++nt)
            #pragma unroll
            for (int r = 0; r < 4; ++r) acc[mt][nt][r] = 0.f;

    int smrow[4], schunk[4], sbase[4];
    #pragma unroll
    for (int i = 0; i < 4; ++i) {
        int linear = (wave * 4 + i) * 64 + lane;
        smrow[i] = linear >> 3;
        schunk[i] = (linear & 7) ^ (smrow[i] & 7);
        sbase[i] = (wave * 4 + i) * 512;
    }

    for (int k0 = 0; k0 < 1024; k0 += 64) {
        #pragma unroll
        for (int i = 0; i < 4; ++i) {
            gload_lds16(A + (size_t)(m0 + smrow[i]) * 1024 + k0 + schunk[i] * 8,
                        As + sbase[i]);
            gload_lds16(BT + (size_t)(n0 + smrow[i]) * 1024 + k0 + schunk[i] * 8,
                        Bs + sbase[i]);
        }
        __syncthreads();
        #pragma unroll
        for (int kk = 0; kk < 2; ++kk) {
            bf16x8 am[4], bn[4];
            #pragma unroll
            for (int mt = 0; mt < 4; ++mt) {
                int row = wm * 64 + mt * 16 + l16;
                int c = (kk * 4 + quad) ^ (row & 7);
                am[mt] = *(const bf16x8*)(As + row * 64 + c * 8);
            }
            #pragma unroll
            for (int nt = 0; nt < 4; ++nt) {
                int row = wn * 64 + nt * 16 + l16;
                int c = (kk * 4 + quad) ^ (row & 7);
                bn[nt] = *(const bf16x8*)(Bs + row * 64 + c * 8);
            }
            #pragma unroll
            for (int mt = 0; mt < 4; ++mt)
                #pragma unroll
                for (int nt = 0; nt < 4; ++nt)
                    acc[mt][nt] = __builtin_amdgcn_mfma_f32_16x16x32_bf16(
                        am[mt], bn[nt], acc[mt][nt], 0, 0, 0);
        }
        __syncthreads();
    }

    const int sec = n0 >> 10;                // block-uniform: 0=Q, 1=K, 2=V
    if (sec < 2) {
        __bf16* __restrict__ O = (sec == 0) ? Oq : Ok;
        const float scale = (sec == 0) ? QSCALE : 1.f;
        #pragma unroll
        for (int nt = 0; nt < 4; ++nt) {
            const int col = n0 + wn * 64 + nt * 16 + l16;
            const float bv = bias[col];
            const int f = col & 1023;
            const int h = f >> 6, d = f & 63;
            #pragma unroll
            for (int mt = 0; mt < 4; ++mt)
                #pragma unroll
                for (int r = 0; r < 4; ++r) {
                    const int row = m0 + wm * 64 + mt * 16 + quad * 4 + r;
                    const float v = (acc[mt][nt][r] + bv) * scale;
                    const int t = row >> 1, b = row & 1;
                    const int bh = b * NHEAD + h;
                    O[((size_t)bh * TSEQ + t) * HDIM + d] = (__bf16)v;
                }
        }
    } else {
        // V: acc -> LDS (stride 131, odd -> transpose reads 2-way max),
        // barrier, transposed coalesced store to Vt [bh][d][t]
        #pragma unroll
        for (int nt = 0; nt < 4; ++nt) {
            const int lc = wn * 64 + nt * 16 + l16;
            const float bv = bias[n0 + lc];
            #pragma unroll
            for (int mt = 0; mt < 4; ++mt)
                #pragma unroll
                for (int r = 0; r < 4; ++r) {
                    const int ml = wm * 64 + mt * 16 + quad * 4 + r;
                    Tt[ml * 131 + lc] = (__bf16)(acc[mt][nt][r] + bv);
                }
        }
        __syncthreads();
        // wave -> (b, h_local); rows ml = 2*t_local + b, cols lc = hl*64 + d
        const int b = wave & 1, hl = wave >> 1;
        const int bh = b * NHEAD + ((n0 - 2048) >> 6) + hl;
        const int t0g = m0 >> 1;
        __bf16* dstbase = Vt + (size_t)bh * HDIM * TSEQ + t0g;
        const int dq = lane >> 3;          // d low bits 0..7
        const int tb = (lane & 7) * 8;     // t chunk base
        #pragma unroll
        for (int p = 0; p < 8; ++p) {
            const int d = dq + 8 * p;
            bf16x8 o;
            #pragma unroll
            for (int jj = 0; jj < 8; ++jj)
                o[jj] = Tt[(2 * (tb + jj) + b) * 131 + hl * 64 + d];
            *(bf16x8*)(dstbase + (size_t)d * TSEQ + tb) = o;
        }
    }
}

// ---------------------------------------------------------------------------
// MFMA flash attention v14 = v12 (R8-proven 50.5us) + T5 s_setprio around
// the QK and PV MFMA clusters. The 2 independent blocks per SIMD sit at
// different phases -> the CU scheduler can prefer the MFMA-entering wave
// (catalog: +4-7% on attn-like structures; null only on lockstep GEMM).
// Fused-normalize, full 2048-key softmax, 4 waves x 32 q, grid 512 =
// 2 blocks/CU, swapped 32x32x16 QK^T + in-register softmax. LDS 32.5KB.
// ---------------------------------------------------------------------------
__global__ __launch_bounds__(256, 2) void attn_mfma_kernel(
    const __bf16* __restrict__ Q, const __bf16* __restrict__ K,
    const __bf16* __restrict__ Vt, __bf16* __restrict__ Ob)
{
    __shared__ __align__(16) __bf16 Ks[2][64 * 64];     // 16KB
    __shared__ __align__(16) __bf16 Vs[2][64 * 64];     // 16KB
    __shared__ float Linv[4][32];                       // 512B

    const int tid  = threadIdx.x;
    const int wave = tid >> 6;
    const int lane = tid & 63;
    const int l31  = lane & 31;
    const int hi   = lane >> 5;
    const int m7   = l31 & 7;

    // XCD-aware decode: hardware assigns XCD = blockIdx.x % 8 (round-robin).
    const int lid = blockIdx.x;        // 0..511
    const int xcd = lid & 7;
    const int j   = lid >> 3;          // 0..63 within XCD
    const int bh  = xcd * 4 + (j >> 4);    // 0..31
    const int qb  = j & 15;            // q-tile 0..15

    const int q0 = qb * 128 + wave * 32;

    // Q fragments (B-operand): col = q = l31, contraction d = 16c + 8hi + j
    bf16x8 qf[4];
    {
        const __bf16* Qrow = Q + ((size_t)bh * TSEQ + q0 + l31) * HDIM + 8 * hi;
        #pragma unroll
        for (int c = 0; c < 4; ++c)
            qf[c] = *(const bf16x8*)(Qrow + 16 * c);
    }

    // O accumulators: per d-tile dt, lane holds col d = 32*dt + l31,
    // rows q = (r&3) + 8*(r>>2) + 4*hi
    f32x16 Oacc[2];
    #pragma unroll
    for (int dt = 0; dt < 2; ++dt)
        #pragma unroll
        for (int r = 0; r < 16; ++r) Oacc[dt][r] = 0.f;
    float l4[4] = {0.f, 0.f, 0.f, 0.f};

    const __bf16* Kbase = K + (size_t)bh * TSEQ * HDIM;
    const __bf16* Vbase = Vt + (size_t)bh * HDIM * TSEQ;

    int srow[2], schk[2];
    #pragma unroll
    for (int i = 0; i < 2; ++i) {
        const int s = wave * 2 + i;
        srow[i] = s * 8 + (lane >> 3);
        schk[i] = (lane & 7) ^ (srow[i] & 7);
    }

#define STAGE(buf, kt)                                                        \
    {                                                                         \
        _Pragma("unroll")                                                     \
        for (int i = 0; i < 2; ++i) {                                         \
            const int s = wave * 2 + i;                                       \
            gload_lds16(Kbase + (size_t)((kt) * 64 + srow[i]) * HDIM          \
                            + schk[i] * 8,                                    \
                        &Ks[buf][s * 512]);                                   \
            gload_lds16(Vbase + (size_t)srow[i] * TSEQ + (kt) * 64            \
                            + schk[i] * 8,                                    \
                        &Vs[buf][s * 512]);                                   \
        }                                                                     \
    }

    STAGE(0, 0);

    for (int kt = 0; kt < NT; ++kt) {
        const int b = kt & 1;
        __syncthreads();                    // staging of buf b complete
        if (kt + 1 < NT) STAGE(b ^ 1, kt + 1);  // overlap next-tile loads

        // --- QK^T (swapped): S^T[k][q] per 32-key subtile, then softmax ---
        u32x4 pa[4];     // PV A-fragments, k-subtiles of 16
        #pragma unroll
        for (int s = 0; s < 2; ++s) {
            f32x16 sacc;
            #pragma unroll
            for (int r = 0; r < 16; ++r) sacc[r] = 0.f;
            __builtin_amdgcn_s_setprio(1);
            #pragma unroll
            for (int c = 0; c < 4; ++c) {
                // A-operand: row k = 32s + l31, contraction d = 16c + 8hi + j
                bf16x8 kf = *(const bf16x8*)(
                    &Ks[b][(32 * s + l31) * 64 + (((c << 1) | hi) ^ m7) * 8]);
                sacc = __builtin_amdgcn_mfma_f32_32x32x16_bf16(
                    kf, qf[c], sacc, 0, 0, 0);
            }
            __builtin_amdgcn_s_setprio(0);
            // lane holds S^T[k = (r&3)+8*(r>>2)+4hi + 32s][q = l31]
            float p[16];
            #pragma unroll
            for (int r = 0; r < 16; ++r) {
                p[r] = fast_exp2(sacc[r]);
                l4[r & 3] += p[r];
            }
            unsigned x[8];
            #pragma unroll
            for (int i = 0; i < 8; ++i)
                x[i] = cvt_pk_bf16(p[2 * i], p[2 * i + 1]);
            // exchange k-halves between lane and lane^32 (same q)
            swap32(x[0], x[2]); swap32(x[1], x[3]);
            swap32(x[4], x[6]); swap32(x[5], x[7]);
            pa[2 * s][0] = x[0]; pa[2 * s][1] = x[1];
            pa[2 * s][2] = x[2]; pa[2 * s][3] = x[3];
            pa[2 * s + 1][0] = x[4]; pa[2 * s + 1][1] = x[5];
            pa[2 * s + 1][2] = x[6]; pa[2 * s + 1][3] = x[7];
        }

        // --- PV: O[q][d] += P[q][k] V[k][d], 4 k-subtiles x 2 d-tiles ---
        __builtin_amdgcn_s_setprio(1);
        #pragma unroll
        for (int dt = 0; dt < 2; ++dt)
            #pragma unroll
            for (int ks = 0; ks < 4; ++ks) {
                // B-operand: col d = 32dt + l31, contraction k' = 8hi + j
                bf16x8 vf = *(const bf16x8*)(
                    &Vs[b][(dt * 32 + l31) * 64 + (((ks << 1) | hi) ^ m7) * 8]);
                Oacc[dt] = __builtin_amdgcn_mfma_f32_32x32x16_bf16(
                    as_bf16x8(pa[ks]), vf, Oacc[dt], 0, 0, 0);
            }
        __builtin_amdgcn_s_setprio(0);
    }
#undef STAGE

    // l: lane and lane^32 hold complementary k-halves of the same q; build
    // per-wave inv-l broadcast table (acc rows need OTHER lanes' q values)
    {
        float v = (l4[0] + l4[1]) + (l4[2] + l4[3]);
        v += __shfl_xor(v, 32);
        if (hi == 0)
            Linv[wave][l31] = 1.f / v;
    }
    __syncthreads();

    // normalized O, bf16, [bh][t][d] flat -- final output of attention
    const size_t base = ((size_t)bh * TSEQ + q0) * HDIM;
    #pragma unroll
    for (int dt = 0; dt < 2; ++dt)
        #pragma unroll
        for (int r = 0; r < 16; ++r) {
            const int ql = (r & 3) + 8 * (r >> 2) + 4 * hi;
            const float inv = Linv[wave][ql];   // same addr across l31: bcast
            Ob[base + (size_t)ql * HDIM + dt * 32 + l31] =
                (__bf16)(Oacc[dt][r] * inv);
        }
}

// ---------------------------------------------------------------------------
// bf16 MFMA GEMM for out-projection, BM=128 BN=64 BK=64: per wave 64x32
// output (4x2 of 16x16), 16 MFMA : 12 ds_read per K-step, barrier amortized
// 2x. grid (16, 32) = 512 blocks = 2/CU, LDS 24KB. Epilogue +bias, fp32.
// ---------------------------------------------------------------------------
__global__ __launch_bounds__(256) void gemm_out_kernel(
    const __bf16* __restrict__ A, const __bf16* __restrict__ BT,
    const float* __restrict__ bias, float* __restrict__ out)
{
    __shared__ __align__(16) __bf16 As[128 * 64];
    __shared__ __align__(16) __bf16 Bs[64 * 64];
    const int tid = threadIdx.x;
    const int wave = tid >> 6, lane = tid & 63;
    const int l16 = lane & 15, quad = lane >> 4;
    const int wm = wave >> 1, wn = wave & 1;
    const int m0 = blockIdx.y * 128, n0 = blockIdx.x * 64;

    f32x4 acc[4][2];
    #pragma unroll
    for (int mt = 0; mt < 4; ++mt)
        #pragma unroll
        for (int nt = 0; nt < 2; ++nt)
            #pragma unroll
            for (int r = 0; r < 4; ++r) acc[mt][nt][r] = 0.f;

    // A staging: 4 chunks/thread covering 128 rows
    int amrow[4], amchk[4], ambase[4];
    #pragma unroll
    for (int i = 0; i < 4; ++i) {
        int linear = (wave * 4 + i) * 64 + lane;
        amrow[i] = linear >> 3;
        amchk[i] = (linear & 7) ^ (amrow[i] & 7);
        ambase[i] = (wave * 4 + i) * 512;
    }
    // B staging: 2 chunks/thread covering 64 rows
    int brow[2], bchk[2], bbase[2];
    #pragma unroll
    for (int i = 0; i < 2; ++i) {
        const int s = wave * 2 + i;
        brow[i] = s * 8 + (lane >> 3);
        bchk[i] = (lane & 7) ^ (brow[i] & 7);
        bbase[i] = s * 512;
    }

    for (int k0 = 0; k0 < 1024; k0 += 64) {
        #pragma unroll
        for (int i = 0; i < 4; ++i)
            gload_lds16(A + (size_t)(m0 + amrow[i]) * 1024 + k0 + amchk[i] * 8,
                        As + ambase[i]);
        #pragma unroll
        for (int i = 0; i < 2; ++i)
            gload_lds16(BT + (size_t)(n0 + brow[i]) * 1024 + k0 + bchk[i] * 8,
                        Bs + bbase[i]);
        __syncthreads();
        #pragma unroll
        for (int kk = 0; kk < 2; ++kk) {
            bf16x8 am[4], bn[2];
            #pragma unroll
            for (int mt = 0; mt < 4; ++mt) {
                int row = wm * 64 + mt * 16 + l16;
                int c = (kk * 4 + quad) ^ (row & 7);
                am[mt] = *(const bf16x8*)(As + row * 64 + c * 8);
            }
            #pragma unroll
            for (int nt = 0; nt < 2; ++nt) {
                int row = wn * 32 + nt * 16 + l16;
                int c = (kk * 4 + quad) ^ (row & 7);
                bn[nt] = *(const bf16x8*)(Bs + row * 64 + c * 8);
            }
            #pragma unroll
            for (int mt = 0; mt < 4; ++mt)
                #pragma unroll
                for (int nt = 0; nt < 2; ++nt)
                    acc[mt][nt] = __builtin_amdgcn_mfma_f32_16x16x32_bf16(
                        am[mt], bn[nt], acc[mt][nt], 0, 0, 0);
        }
        __syncthreads();
    }

    #pragma unroll
    for (int nt = 0; nt < 2; ++nt) {
        const int col = n0 + wn * 32 + nt * 16 + l16;
        const float bv = bias[col];
        #pragma unroll
        for (int mt = 0; mt < 4; ++mt)
            #pragma unroll
            for (int r = 0; r < 4; ++r) {
                const int row = m0 + wm * 64 + mt * 16 + quad * 4 + r;
                out[(size_t)row * 1024 + col] = acc[mt][nt][r] + bv;
            }
    }
}

// ---------------------------------------------------------------------------
extern "C" void kernel_launch(void* const* d_in, const int* in_sizes, int n_in,
                              void* d_out, int out_size, void* d_ws, size_t ws_size,
                              hipStream_t stream) {
    const float* x     = (const float*)d_in[0];   // (2048, 2, 1024)
    const float* w_in  = (const float*)d_in[1];   // (1024, 3072)
    const float* b_in  = (const float*)d_in[2];   // (3072,)
    const float* w_out = (const float*)d_in[3];   // (1024, 1024)
    const float* b_out = (const float*)d_in[4];   // (1024,)
    float* out = (float*)d_out;                   // (2, 2048, 1024) flat 4096x1024

    const size_t M1 = (size_t)1024 * 1024;
    __bf16* ws  = (__bf16*)d_ws;
    __bf16* xb  = ws;                 // 4M elem
    __bf16* wiT = xb  + 4 * M1;       // 3M
    __bf16* whT = wiT + 3 * M1;       // 1M
    __bf16* Qb  = whT + 1 * M1;       // 4M
    __bf16* Kb  = Qb  + 4 * M1;       // 4M
    __bf16* Vt  = Kb  + 4 * M1;       // 4M  (written transposed by gemm_qkv)
    __bf16* Ob  = xb;                 // alias: xb dead after gemm_qkv

    prep_kernel<<<8192, 256, 0, stream>>>(x, w_in, w_out, xb, wiT, whT);
    gemm_qkv_kernel<<<dim3(24, 32), 256, 0, stream>>>(
        xb, wiT, b_in, Qb, Kb, Vt);
    attn_mfma_kernel<<<dim3(512), 256, 0, stream>>>(
        Qb, Kb, Vt, Ob);
    gemm_out_kernel<<<dim3(16, 32), 256, 0, stream>>>(
        Ob, whT, b_out, out);
}